// Round 7
// baseline (206.444 us; speedup 1.0000x reference)
//
#include <hip/hip_runtime.h>
#include <hip/hip_bf16.h>

// RelationAwareSelfAttention  N=500, DM=DK=DV=2048, KWIN=10
// Round 7: gemm staging via __builtin_amdgcn_global_load_lds (16B, m97
// structure) -> LDS-pipe pressure halved; QKV/Vt un-split with direct bf16
// epilogue (reduce pass deleted). 7 launches.

#define N_TOK 500
#define MP 512
#define DM 2048
#define KWIN_ 10
#define NREL 21

typedef __hip_bfloat16 bf16;
typedef __attribute__((ext_vector_type(8))) short short8;
typedef __attribute__((ext_vector_type(4))) float floatx4;

#define NS 262144L  // 512*512
#define NY 1048576L // 512*2048

#define GLOADLDS(g, l)                                        \
  __builtin_amdgcn_global_load_lds(                           \
      (const __attribute__((address_space(1))) void*)(g),     \
      (__attribute__((address_space(3))) void*)(l), 16, 0, 0)

__device__ inline float bfj(const short8& v, int j) {
  return __bfloat162float(((const bf16*)&v)[j]);
}

// ---------------- prep: weights transpose+cvt, X/wk cvt ----------------
__global__ __launch_bounds__(256) void prep(
    const float* __restrict__ Wq, const float* __restrict__ Wk,
    const float* __restrict__ Wv, const float* __restrict__ Wo,
    const float* __restrict__ X, const float* __restrict__ wk,
    bf16* __restrict__ WqkT, bf16* __restrict__ WvT, bf16* __restrict__ WoT,
    bf16* __restrict__ Xb, bf16* __restrict__ wkb) {
  int z = blockIdx.z;
  int tid = threadIdx.x;
  if (z == 4) {  // row conversions
    int row = blockIdx.y * 32 + blockIdx.x;
    int c0 = tid * 8;
    bf16 v[8];
    if (row < MP) {
      if (row < N_TOK) {
        const float* p = X + (long)row * DM + c0;
#pragma unroll
        for (int j = 0; j < 8; ++j) v[j] = __float2bfloat16(p[j]);
      } else {
#pragma unroll
        for (int j = 0; j < 8; ++j) v[j] = __float2bfloat16(0.f);
      }
      *(short8*)(Xb + (long)row * DM + c0) = *(short8*)v;
    } else if (row < MP + NREL) {
      int r = row - MP;
      const float* p = wk + (long)r * DM + c0;
#pragma unroll
      for (int j = 0; j < 8; ++j) v[j] = __float2bfloat16(p[j]);
      *(short8*)(wkb + (long)r * DM + c0) = *(short8*)v;
    }
    return;
  }
  const float* W = (z == 0) ? Wq : (z == 1) ? Wk : (z == 2) ? Wv : Wo;
  bf16* Out = (z == 0) ? WqkT
            : (z == 1) ? (WqkT + (long)DM * DM)
            : (z == 2) ? WvT : WoT;
  __shared__ float t[64][68];  // XOR-swizzled granules, conflict-free both ways
  int k0 = blockIdx.y * 64, n0 = blockIdx.x * 64;
  int rr = tid >> 4, cc = (tid & 15) * 4;
  int gsw = cc >> 2;
#pragma unroll
  for (int p = 0; p < 4; ++p) {
    int r = rr + 16 * p;
    float4 v = *(const float4*)(W + (long)(k0 + r) * DM + n0 + cc);
    *(float4*)&t[r][(gsw ^ (r & 3)) * 4] = v;
  }
  __syncthreads();
#pragma unroll
  for (int s0 = 0; s0 < 2; ++s0) {
    int s = tid + s0 * 256;
    int n = s >> 3, c = s & 7;
    bf16 v[8];
#pragma unroll
    for (int j = 0; j < 8; ++j) {
      int rowt = c * 8 + j;
      int col = ((n >> 2) ^ (rowt & 3)) * 4 + (n & 3);
      v[j] = __float2bfloat16(t[rowt][col]);
    }
    *(short8*)(Out + (long)(n0 + n) * DM + k0 + c * 8) = *(short8*)v;
  }
}

// ------- gemm core: 128x128 tile, 4 waves of 64x64, global_load_lds -------
// NT: C[M,N] = A[M,K] @ B[N,K]^T over K-slice [kStart, kStart+kLen).
// OUT: 0 -> f32 store, 1 -> bf16 store. All dims padded, no guards.
template <int OUT>
__device__ __forceinline__ void gemm_core(
    const bf16* __restrict__ A, int lda, const bf16* __restrict__ B, int ldb,
    float* __restrict__ Cf, bf16* __restrict__ Cb, int ldc, int kStart,
    int kLen, int row0, int col0) {
  // NO padding: pitch 64 B so load_lds lane offset l*16B == [row l/4][(l%4)*8]
  __shared__ __align__(16) bf16 As[128][32];
  __shared__ __align__(16) bf16 Bs[128][32];
  int tid = threadIdx.x;
  int lane = tid & 63, w = tid >> 6;
  int wr = (w & 1) * 64, wc = (w >> 1) * 64;
  int l16 = lane & 15, l4 = lane >> 4;
  // staging: wave w stages rows [32w, 32w+32) of both tiles, 2 chunks each
  int srow = w * 32 + (lane >> 2);
  int scol = (lane & 3) * 8;
  const bf16* ga0 = A + (long)(row0 + srow) * lda + kStart + scol;
  const bf16* ga1 = ga0 + 16 * (long)lda;
  const bf16* gb0 = B + (long)(col0 + srow) * ldb + kStart + scol;
  const bf16* gb1 = gb0 + 16 * (long)ldb;
  bf16* la0 = &As[w * 32][0];
  bf16* la1 = &As[w * 32 + 16][0];
  bf16* lb0 = &Bs[w * 32][0];
  bf16* lb1 = &Bs[w * 32 + 16][0];
  floatx4 acc[4][4] = {};
  for (int k0 = 0; k0 < kLen; k0 += 32) {
    GLOADLDS(ga0 + k0, la0);
    GLOADLDS(ga1 + k0, la1);
    GLOADLDS(gb0 + k0, lb0);
    GLOADLDS(gb1 + k0, lb1);
    __syncthreads();  // drains vmcnt -> staged data visible
    short8 af[4], bg[4];
#pragma unroll
    for (int g = 0; g < 4; ++g)
      af[g] = *(short8*)&As[wr + g * 16 + l16][l4 * 8];
#pragma unroll
    for (int g = 0; g < 4; ++g)
      bg[g] = *(short8*)&Bs[wc + g * 16 + l16][l4 * 8];
#pragma unroll
    for (int g = 0; g < 4; ++g)
#pragma unroll
      for (int h = 0; h < 4; ++h)
        acc[g][h] =
            __builtin_amdgcn_mfma_f32_16x16x32_bf16(af[g], bg[h], acc[g][h], 0, 0, 0);
    __syncthreads();  // reads done before next iter's DMA overwrites
  }
  // C/D layout: col = lane&15, row = (lane>>4)*4 + i  [m89-verified]
#pragma unroll
  for (int g = 0; g < 4; ++g)
#pragma unroll
    for (int h = 0; h < 4; ++h)
#pragma unroll
      for (int i = 0; i < 4; ++i) {
        long r = row0 + wr + g * 16 + l4 * 4 + i;
        long c = col0 + wc + h * 16 + l16;
        if (OUT == 0)
          Cf[r * ldc + c] = acc[g][h][i];
        else
          Cb[r * ldc + c] = __float2bfloat16(acc[g][h][i]);
      }
}

// Merged QK (128 blocks) + Vt (64 blocks), full K, direct bf16 epilogue.
__global__ __launch_bounds__(256, 2) void gemm_qkvt(
    const bf16* __restrict__ Xb, const bf16* __restrict__ WqkT,
    const bf16* __restrict__ WvT, bf16* __restrict__ QKbf,
    bf16* __restrict__ Vtb) {
  int id = blockIdx.x;
  if (id < 128) {  // QK: C[512,4096] = Xb @ WqkT^T
    int col0 = (id & 31) * 128, row0 = (id >> 5) * 128;
    gemm_core<1>(Xb, DM, WqkT, DM, nullptr, QKbf, 4096, 0, DM, row0, col0);
  } else {  // Vt: C[2048,512] = WvT @ Xb^T
    int t = id - 128;
    int col0 = (t & 3) * 128, row0 = (t >> 2) * 128;
    gemm_core<1>(WvT, DM, Xb, DM, nullptr, Vtb, MP, 0, DM, row0, col0);
  }
}

// Generic split-K gemm. grid (N/128, M/128, splits).
template <int OUT>
__global__ __launch_bounds__(256, 2) void gemm_k(
    const bf16* __restrict__ A, int lda, const bf16* __restrict__ B, int ldb,
    float* __restrict__ Cf, bf16* __restrict__ Cb, int ldc, int sliceK,
    long cstride) {
  float* cf = (OUT == 0) ? Cf + (long)blockIdx.z * cstride : nullptr;
  gemm_core<OUT>(A, lda, B, ldb, cf, Cb, ldc, blockIdx.z * sliceK, sliceK,
                 blockIdx.y * 128, blockIdx.x * 128);
}

// Yout[<500] = Yp[0] + Yp[1]. grid 500x256.
__global__ __launch_bounds__(256) void reduce_y(const float* __restrict__ Yp,
                                                float* __restrict__ Yout) {
  long e = (long)blockIdx.x * 2048 + threadIdx.x * 8;
  float4 a0 = *(const float4*)(Yp + e), a1 = *(const float4*)(Yp + e + 4);
  float4 b0 = *(const float4*)(Yp + NY + e), b1 = *(const float4*)(Yp + NY + e + 4);
  float4 o0 = {a0.x + b0.x, a0.y + b0.y, a0.z + b0.z, a0.w + b0.w};
  float4 o1 = {a1.x + b1.x, a1.y + b1.y, a1.z + b1.z, a1.w + b1.w};
  *(float4*)(Yout + e) = o0;
  *(float4*)(Yout + e + 4) = o1;
}

// QR (21 dots of K=2048) + sum 4 S-partials + scale + bias + mask + softmax.
__global__ __launch_bounds__(256) void softmax_qr(
    const float* __restrict__ Sp, const bf16* __restrict__ QKbf,
    const bf16* __restrict__ wkb, const int* __restrict__ mask,
    float* __restrict__ Aout, bf16* __restrict__ Abf) {
  int i = blockIdx.x;
  int tid = threadIdx.x;
  if (i >= N_TOK) {  // pad rows of Abf -> 0
    Abf[(long)i * MP + tid] = __float2bfloat16(0.f);
    Abf[(long)i * MP + tid + 256] = __float2bfloat16(0.f);
    return;
  }
  int lane = tid & 63, w = tid >> 6;
  __shared__ float sQR[24];
  __shared__ float red[4];
  short8 q[4];
#pragma unroll
  for (int s = 0; s < 4; ++s)
    q[s] = *(const short8*)(QKbf + (long)i * 4096 + s * 512 + lane * 8);
  for (int r = w; r < NREL; r += 4) {
    float p = 0.f;
#pragma unroll
    for (int s = 0; s < 4; ++s) {
      short8 wv = *(const short8*)(wkb + (long)r * DM + s * 512 + lane * 8);
#pragma unroll
      for (int j = 0; j < 8; ++j) p += bfj(q[s], j) * bfj(wv, j);
    }
#pragma unroll
    for (int o = 32; o > 0; o >>= 1) p += __shfl_down(p, o);
    if (lane == 0) sQR[r] = p;
  }
  __syncthreads();
  const float scale = 0.022097086912079608f;  // 1/sqrt(2048)
  float v0, v1 = -1e30f;
  int j0 = tid, j1 = tid + 256;
  {
    float s = Sp[(long)i * MP + j0] + Sp[NS + (long)i * MP + j0] +
              Sp[2 * NS + (long)i * MP + j0] + Sp[3 * NS + (long)i * MP + j0];
    int rel = j0 - i;
    rel = rel < -KWIN_ ? -KWIN_ : (rel > KWIN_ ? KWIN_ : rel);
    s = scale * (s + sQR[rel + KWIN_]);
    if (mask[(long)i * N_TOK + j0] == 0) s = -1e9f;
    v0 = s;
  }
  if (j1 < N_TOK) {
    float s = Sp[(long)i * MP + j1] + Sp[NS + (long)i * MP + j1] +
              Sp[2 * NS + (long)i * MP + j1] + Sp[3 * NS + (long)i * MP + j1];
    int rel = j1 - i;
    rel = rel < -KWIN_ ? -KWIN_ : (rel > KWIN_ ? KWIN_ : rel);
    s = scale * (s + sQR[rel + KWIN_]);
    if (mask[(long)i * N_TOK + j1] == 0) s = -1e9f;
    v1 = s;
  }
  float mx = fmaxf(v0, v1);
#pragma unroll
  for (int o = 32; o > 0; o >>= 1) mx = fmaxf(mx, __shfl_down(mx, o));
  if (lane == 0) red[w] = mx;
  __syncthreads();
  if (tid == 0) red[0] = fmaxf(fmaxf(red[0], red[1]), fmaxf(red[2], red[3]));
  __syncthreads();
  mx = red[0];
  __syncthreads();
  float e0 = expf(v0 - mx);
  float e1 = (j1 < N_TOK) ? expf(v1 - mx) : 0.f;
  float sum = e0 + e1;
#pragma unroll
  for (int o = 32; o > 0; o >>= 1) sum += __shfl_down(sum, o);
  if (lane == 0) red[w] = sum;
  __syncthreads();
  if (tid == 0) red[0] = red[0] + red[1] + red[2] + red[3];
  __syncthreads();
  float inv = 1.f / red[0];
  float a0 = e0 * inv, a1 = e1 * inv;
  Aout[(long)i * N_TOK + j0] = a0;
  if (j1 < N_TOK) Aout[(long)i * N_TOK + j1] = a1;
  Abf[(long)i * MP + j0] = __float2bfloat16(a0);
  Abf[(long)i * MP + j1] = __float2bfloat16(a1);  // j1>=500 -> 0
}

extern "C" void kernel_launch(void* const* d_in, const int* in_sizes, int n_in,
                              void* d_out, int out_size, void* d_ws,
                              size_t ws_size, hipStream_t stream) {
  const float* X = (const float*)d_in[0];
  const int* mask = (const int*)d_in[1];
  const float* Wq = (const float*)d_in[2];
  const float* Wk = (const float*)d_in[3];
  const float* Wv = (const float*)d_in[4];
  const float* Wo = (const float*)d_in[5];
  const float* wk = (const float*)d_in[6];

  float* Yout = (float*)d_out;            // [500,2048]
  float* Aout = Yout + (long)N_TOK * DM;  // [500,500]

  const long MB = 1 << 20;
  char* p = (char*)d_ws;
  bf16* Xb = (bf16*)p;                    // [512][2048]     2 MB
  bf16* WqkT = (bf16*)(p + 2 * MB);       // [4096][2048]   16 MB
  bf16* WvT = (bf16*)(p + 18 * MB);       // [2048][2048]    8 MB
  bf16* WoT = (bf16*)(p + 26 * MB);       // [2048][2048]    8 MB
  bf16* wkb = (bf16*)(p + 34 * MB);       // [21][2048]
  bf16* QKbf = (bf16*)(p + 35 * MB);      // [512][4096]     4 MB
  bf16* Vtb = (bf16*)(p + 39 * MB);       // [2048][512]     2 MB
  float* Sp = (float*)(p + 41 * MB);      // [4][512][512]   4 MB
  bf16* Abf = (bf16*)(p + 45 * MB);       // [512][512]    0.5 MB
  bf16* AVbf = (bf16*)(p + 46 * MB);      // [512][2048]     2 MB
  float* Yp = (float*)(p + 48 * MB);      // [2][512][2048]  8 MB

  dim3 b256(256);

  // 1. prep: weights -> transposed bf16; X/wk -> bf16
  prep<<<dim3(32, 32, 5), b256, 0, stream>>>(Wq, Wk, Wv, Wo, X, wk, WqkT, WvT,
                                             WoT, Xb, wkb);
  // 2. QK + Vt, full K, bf16 out. 192 blocks.
  gemm_qkvt<<<dim3(192), b256, 0, stream>>>(Xb, WqkT, WvT, QKbf, Vtb);
  // 3. S partials: Q @ K^T, splitK4 (unscaled)
  gemm_k<0><<<dim3(4, 4, 4), b256, 0, stream>>>(QKbf, 4096, QKbf + 2048, 4096,
                                                Sp, nullptr, MP, 512, NS);
  // 4. QR + softmax -> Aout (d_out) + Abf
  softmax_qr<<<dim3(MP), b256, 0, stream>>>(Sp, QKbf, wkb, mask, Aout, Abf);
  // 5. AV = Abf @ Vtb^T -> bf16
  gemm_k<1><<<dim3(16, 4, 1), b256, 0, stream>>>(Abf, MP, Vtb, MP, nullptr,
                                                 AVbf, DM, MP, 0);
  // 6. Y partials: AVbf @ WoT^T, splitK2
  gemm_k<0><<<dim3(16, 4, 2), b256, 0, stream>>>(AVbf, DM, WoT, DM, Yp,
                                                 nullptr, DM, 1024, NY);
  // 7. Y = sum partials -> f32 d_out (rows < 500)
  reduce_y<<<dim3(N_TOK), b256, 0, stream>>>(Yp, Yout);
}

// Round 8
// 196.823 us; speedup vs baseline: 1.0489x; 1.0489x over previous
//
#include <hip/hip_runtime.h>
#include <hip/hip_bf16.h>

// RelationAwareSelfAttention  N=500, DM=DK=DV=2048, KWIN=10
// Round 8: R6 register-prefetch gemm core (R7's load_lds staging regressed
// ~17us in this latency-bound regime) + R7's un-split QKV w/ bf16 epilogue;
// Wo transpose hidden inside AV launch; Y via splitK2 atomicAdd into d_out.
// 6 launches.

#define N_TOK 500
#define MP 512
#define DM 2048
#define KWIN_ 10
#define NREL 21

typedef __hip_bfloat16 bf16;
typedef __attribute__((ext_vector_type(8))) short short8;
typedef __attribute__((ext_vector_type(4))) float floatx4;

#define NS 262144L  // 512*512

__device__ inline float bfj(const short8& v, int j) {
  return __bfloat162float(((const bf16*)&v)[j]);
}

// ---- 64x64 f32->bf16 transposing tile copy (XOR-swizzled, conflict-free) ----
__device__ __forceinline__ void transpose_tile(const float* __restrict__ W,
                                               bf16* __restrict__ Out, int k0,
                                               int n0) {
  __shared__ float t[64][68];
  int tid = threadIdx.x;
  int rr = tid >> 4, cc = (tid & 15) * 4;
  int gsw = cc >> 2;
#pragma unroll
  for (int p = 0; p < 4; ++p) {
    int r = rr + 16 * p;
    float4 v = *(const float4*)(W + (long)(k0 + r) * DM + n0 + cc);
    *(float4*)&t[r][(gsw ^ (r & 3)) * 4] = v;
  }
  __syncthreads();
#pragma unroll
  for (int s0 = 0; s0 < 2; ++s0) {
    int s = tid + s0 * 256;
    int n = s >> 3, c = s & 7;
    bf16 v[8];
#pragma unroll
    for (int j = 0; j < 8; ++j) {
      int rowt = c * 8 + j;
      int col = ((n >> 2) ^ (rowt & 3)) * 4 + (n & 3);
      v[j] = __float2bfloat16(t[rowt][col]);
    }
    *(short8*)(Out + (long)(n0 + n) * DM + k0 + c * 8) = *(short8*)v;
  }
}

// ---------------- prep: Wq/Wk/Wv transpose+cvt, X/wk cvt ----------------
__global__ __launch_bounds__(256) void prep(
    const float* __restrict__ Wq, const float* __restrict__ Wk,
    const float* __restrict__ Wv, const float* __restrict__ X,
    const float* __restrict__ wk, bf16* __restrict__ WqkT,
    bf16* __restrict__ WvT, bf16* __restrict__ Xb, bf16* __restrict__ wkb) {
  int z = blockIdx.z;
  int tid = threadIdx.x;
  if (z == 3) {  // row conversions
    int row = blockIdx.y * 32 + blockIdx.x;
    int c0 = tid * 8;
    bf16 v[8];
    if (row < MP) {
      if (row < N_TOK) {
        const float* p = X + (long)row * DM + c0;
#pragma unroll
        for (int j = 0; j < 8; ++j) v[j] = __float2bfloat16(p[j]);
      } else {
#pragma unroll
        for (int j = 0; j < 8; ++j) v[j] = __float2bfloat16(0.f);
      }
      *(short8*)(Xb + (long)row * DM + c0) = *(short8*)v;
    } else if (row < MP + NREL) {
      int r = row - MP;
      const float* p = wk + (long)r * DM + c0;
#pragma unroll
      for (int j = 0; j < 8; ++j) v[j] = __float2bfloat16(p[j]);
      *(short8*)(wkb + (long)r * DM + c0) = *(short8*)v;
    }
    return;
  }
  const float* W = (z == 0) ? Wq : (z == 1) ? Wk : Wv;
  bf16* Out = (z == 0) ? WqkT : (z == 1) ? (WqkT + (long)DM * DM) : WvT;
  transpose_tile(W, Out, blockIdx.y * 64, blockIdx.x * 64);
}

// ------- gemm core: 128x128 tile, 4 waves of 64x64, register prefetch -------
// NT: C[M,N] = A[M,K] @ B[N,K]^T over K-slice [kStart, kStart+kLen).
// OUT: 0 -> f32 store, 1 -> bf16 store, 2 -> f32 atomicAdd rows < m_store.
template <int OUT>
__device__ __forceinline__ void gemm_core(
    const bf16* __restrict__ A, int lda, const bf16* __restrict__ B, int ldb,
    float* __restrict__ Cf, bf16* __restrict__ Cb, int ldc, int kStart,
    int kLen, int row0, int col0, int m_store) {
  __shared__ __align__(16) bf16 As[128][32];
  __shared__ __align__(16) bf16 Bs[128][32];
  int tid = threadIdx.x;
  int lane = tid & 63, w = tid >> 6;
  int wr = (w & 1) * 64, wc = (w >> 1) * 64;
  int l16 = lane & 15, l4 = lane >> 4;
  int r1 = tid >> 2, c1 = (tid & 3) * 8;
  const bf16* Ab = A + (long)row0 * lda + kStart;
  const bf16* Bb = B + (long)col0 * ldb + kStart;
  const bf16* a1p = Ab + (long)r1 * lda + c1;
  const bf16* a2p = Ab + (long)(r1 + 64) * lda + c1;
  const bf16* b1p = Bb + (long)r1 * ldb + c1;
  const bf16* b2p = Bb + (long)(r1 + 64) * ldb + c1;
  floatx4 acc[4][4] = {};
  short8 pa0 = *(const short8*)a1p, pa1 = *(const short8*)a2p;
  short8 pb0 = *(const short8*)b1p, pb1 = *(const short8*)b2p;
  for (int k0 = 0; k0 < kLen; k0 += 32) {
    if (k0) __syncthreads();
    *(short8*)&As[r1][c1] = pa0;
    *(short8*)&As[r1 + 64][c1] = pa1;
    *(short8*)&Bs[r1][c1] = pb0;
    *(short8*)&Bs[r1 + 64][c1] = pb1;
    __syncthreads();
    int kn = k0 + 32;
    if (kn < kLen) {  // prefetch next slice; HBM latency overlaps LDS+MFMA
      pa0 = *(const short8*)(a1p + kn);
      pa1 = *(const short8*)(a2p + kn);
      pb0 = *(const short8*)(b1p + kn);
      pb1 = *(const short8*)(b2p + kn);
    }
    short8 af[4], bg[4];
#pragma unroll
    for (int g = 0; g < 4; ++g)
      af[g] = *(short8*)&As[wr + g * 16 + l16][l4 * 8];
#pragma unroll
    for (int g = 0; g < 4; ++g)
      bg[g] = *(short8*)&Bs[wc + g * 16 + l16][l4 * 8];
#pragma unroll
    for (int g = 0; g < 4; ++g)
#pragma unroll
      for (int h = 0; h < 4; ++h)
        acc[g][h] =
            __builtin_amdgcn_mfma_f32_16x16x32_bf16(af[g], bg[h], acc[g][h], 0, 0, 0);
  }
  // C/D layout: col = lane&15, row = (lane>>4)*4 + i  [m89-verified]
#pragma unroll
  for (int g = 0; g < 4; ++g)
#pragma unroll
    for (int h = 0; h < 4; ++h)
#pragma unroll
      for (int i = 0; i < 4; ++i) {
        long r = row0 + wr + g * 16 + l4 * 4 + i;
        long c = col0 + wc + h * 16 + l16;
        if (OUT == 0)
          Cf[r * ldc + c] = acc[g][h][i];
        else if (OUT == 1)
          Cb[r * ldc + c] = __float2bfloat16(acc[g][h][i]);
        else {
          if (r < m_store) atomicAdd(&Cf[r * ldc + c], acc[g][h][i]);
        }
      }
}

// Merged QK (128 blocks) + Vt (64 blocks), full K, direct bf16 epilogue.
__global__ __launch_bounds__(256, 2) void gemm_qkvt(
    const bf16* __restrict__ Xb, const bf16* __restrict__ WqkT,
    const bf16* __restrict__ WvT, bf16* __restrict__ QKbf,
    bf16* __restrict__ Vtb) {
  int id = blockIdx.x;
  if (id < 128) {  // QK: C[512,4096] = Xb @ WqkT^T
    int col0 = (id & 31) * 128, row0 = (id >> 5) * 128;
    gemm_core<1>(Xb, DM, WqkT, DM, nullptr, QKbf, 4096, 0, DM, row0, col0, 0);
  } else {  // Vt: C[2048,512] = WvT @ Xb^T
    int t = id - 128;
    int col0 = (t & 3) * 128, row0 = (t >> 2) * 128;
    gemm_core<1>(WvT, DM, Xb, DM, nullptr, Vtb, MP, 0, DM, row0, col0, 0);
  }
}

// S partials: Q @ K^T, splitK4. grid (4,4,4).
__global__ __launch_bounds__(256, 2) void gemm_s(const bf16* __restrict__ QKbf,
                                                 float* __restrict__ Sp) {
  gemm_core<0>(QKbf, 4096, QKbf + 2048, 4096, Sp + (long)blockIdx.z * NS,
               nullptr, MP, blockIdx.z * 512, 512, blockIdx.y * 128,
               blockIdx.x * 128, 0);
}

// AV gemm (64 blocks) + Wo transpose (1024 blocks) in one launch.
__global__ __launch_bounds__(256, 2) void gemm_av_wot(
    const bf16* __restrict__ Abf, const bf16* __restrict__ Vtb,
    bf16* __restrict__ AVbf, const float* __restrict__ Wo,
    bf16* __restrict__ WoT) {
  int id = blockIdx.x;
  if (id < 64) {  // AV = Abf @ Vtb^T  [512,2048], K=512
    int col0 = (id & 15) * 128, row0 = (id >> 4) * 128;
    gemm_core<1>(Abf, MP, Vtb, MP, nullptr, AVbf, DM, 0, MP, row0, col0, 0);
  } else {  // WoT tile
    int t = id - 64;
    transpose_tile(Wo, WoT, (t >> 5) * 64, (t & 31) * 64);
  }
}

// Y: AVbf @ WoT^T, splitK2, atomicAdd into pre-zeroed Yout rows < 500.
__global__ __launch_bounds__(256, 2) void gemm_y(const bf16* __restrict__ AVbf,
                                                 const bf16* __restrict__ WoT,
                                                 float* __restrict__ Yout) {
  gemm_core<2>(AVbf, DM, WoT, DM, Yout, nullptr, DM, blockIdx.z * 1024, 1024,
               blockIdx.y * 128, blockIdx.x * 128, N_TOK);
}

// QR (21 dots of K=2048) + sum 4 S-partials + scale + bias + mask + softmax.
// Also zeroes Yout row i (for gemm_y's atomicAdd).
__global__ __launch_bounds__(256) void softmax_qr(
    const float* __restrict__ Sp, const bf16* __restrict__ QKbf,
    const bf16* __restrict__ wkb, const int* __restrict__ mask,
    float* __restrict__ Aout, bf16* __restrict__ Abf,
    float* __restrict__ Yout) {
  int i = blockIdx.x;
  int tid = threadIdx.x;
  if (i >= N_TOK) {  // pad rows of Abf -> 0
    Abf[(long)i * MP + tid] = __float2bfloat16(0.f);
    Abf[(long)i * MP + tid + 256] = __float2bfloat16(0.f);
    return;
  }
  {  // zero Y row i (poisoned 0xAA by harness; gemm_y accumulates)
    float4 z4 = {0.f, 0.f, 0.f, 0.f};
    float* yr = Yout + (long)i * DM + tid * 8;
    *(float4*)yr = z4;
    *(float4*)(yr + 4) = z4;
  }
  int lane = tid & 63, w = tid >> 6;
  __shared__ float sQR[24];
  __shared__ float red[4];
  short8 q[4];
#pragma unroll
  for (int s = 0; s < 4; ++s)
    q[s] = *(const short8*)(QKbf + (long)i * 4096 + s * 512 + lane * 8);
  for (int r = w; r < NREL; r += 4) {
    float p = 0.f;
#pragma unroll
    for (int s = 0; s < 4; ++s) {
      short8 wv = *(const short8*)(wkb + (long)r * DM + s * 512 + lane * 8);
#pragma unroll
      for (int j = 0; j < 8; ++j) p += bfj(q[s], j) * bfj(wv, j);
    }
#pragma unroll
    for (int o = 32; o > 0; o >>= 1) p += __shfl_down(p, o);
    if (lane == 0) sQR[r] = p;
  }
  __syncthreads();
  const float scale = 0.022097086912079608f;  // 1/sqrt(2048)
  float v0, v1 = -1e30f;
  int j0 = tid, j1 = tid + 256;
  {
    float s = Sp[(long)i * MP + j0] + Sp[NS + (long)i * MP + j0] +
              Sp[2 * NS + (long)i * MP + j0] + Sp[3 * NS + (long)i * MP + j0];
    int rel = j0 - i;
    rel = rel < -KWIN_ ? -KWIN_ : (rel > KWIN_ ? KWIN_ : rel);
    s = scale * (s + sQR[rel + KWIN_]);
    if (mask[(long)i * N_TOK + j0] == 0) s = -1e9f;
    v0 = s;
  }
  if (j1 < N_TOK) {
    float s = Sp[(long)i * MP + j1] + Sp[NS + (long)i * MP + j1] +
              Sp[2 * NS + (long)i * MP + j1] + Sp[3 * NS + (long)i * MP + j1];
    int rel = j1 - i;
    rel = rel < -KWIN_ ? -KWIN_ : (rel > KWIN_ ? KWIN_ : rel);
    s = scale * (s + sQR[rel + KWIN_]);
    if (mask[(long)i * N_TOK + j1] == 0) s = -1e9f;
    v1 = s;
  }
  float mx = fmaxf(v0, v1);
#pragma unroll
  for (int o = 32; o > 0; o >>= 1) mx = fmaxf(mx, __shfl_down(mx, o));
  if (lane == 0) red[w] = mx;
  __syncthreads();
  if (tid == 0) red[0] = fmaxf(fmaxf(red[0], red[1]), fmaxf(red[2], red[3]));
  __syncthreads();
  mx = red[0];
  __syncthreads();
  float e0 = expf(v0 - mx);
  float e1 = (j1 < N_TOK) ? expf(v1 - mx) : 0.f;
  float sum = e0 + e1;
#pragma unroll
  for (int o = 32; o > 0; o >>= 1) sum += __shfl_down(sum, o);
  if (lane == 0) red[w] = sum;
  __syncthreads();
  if (tid == 0) red[0] = red[0] + red[1] + red[2] + red[3];
  __syncthreads();
  float inv = 1.f / red[0];
  float a0 = e0 * inv, a1 = e1 * inv;
  Aout[(long)i * N_TOK + j0] = a0;
  if (j1 < N_TOK) Aout[(long)i * N_TOK + j1] = a1;
  Abf[(long)i * MP + j0] = __float2bfloat16(a0);
  Abf[(long)i * MP + j1] = __float2bfloat16(a1);  // j1>=500 -> 0
}

extern "C" void kernel_launch(void* const* d_in, const int* in_sizes, int n_in,
                              void* d_out, int out_size, void* d_ws,
                              size_t ws_size, hipStream_t stream) {
  const float* X = (const float*)d_in[0];
  const int* mask = (const int*)d_in[1];
  const float* Wq = (const float*)d_in[2];
  const float* Wk = (const float*)d_in[3];
  const float* Wv = (const float*)d_in[4];
  const float* Wo = (const float*)d_in[5];
  const float* wk = (const float*)d_in[6];

  float* Yout = (float*)d_out;            // [500,2048]
  float* Aout = Yout + (long)N_TOK * DM;  // [500,500]

  const long MB = 1 << 20;
  char* p = (char*)d_ws;
  bf16* Xb = (bf16*)p;                    // [512][2048]     2 MB
  bf16* WqkT = (bf16*)(p + 2 * MB);       // [4096][2048]   16 MB
  bf16* WvT = (bf16*)(p + 18 * MB);       // [2048][2048]    8 MB
  bf16* WoT = (bf16*)(p + 26 * MB);       // [2048][2048]    8 MB
  bf16* wkb = (bf16*)(p + 34 * MB);       // [21][2048]
  bf16* QKbf = (bf16*)(p + 35 * MB);      // [512][4096]     4 MB
  bf16* Vtb = (bf16*)(p + 39 * MB);       // [2048][512]     2 MB
  float* Sp = (float*)(p + 41 * MB);      // [4][512][512]   4 MB
  bf16* Abf = (bf16*)(p + 45 * MB);       // [512][512]    0.5 MB
  bf16* AVbf = (bf16*)(p + 46 * MB);      // [512][2048]     2 MB

  dim3 b256(256);

  // 1. prep: Wq/Wk/Wv -> transposed bf16; X/wk -> bf16
  prep<<<dim3(32, 32, 4), b256, 0, stream>>>(Wq, Wk, Wv, X, wk, WqkT, WvT, Xb,
                                             wkb);
  // 2. QK + Vt, full K, bf16 out. 192 blocks.
  gemm_qkvt<<<dim3(192), b256, 0, stream>>>(Xb, WqkT, WvT, QKbf, Vtb);
  // 3. S partials: Q @ K^T, splitK4 (unscaled)
  gemm_s<<<dim3(4, 4, 4), b256, 0, stream>>>(QKbf, Sp);
  // 4. QR + softmax -> Aout (d_out) + Abf; zeroes Y rows
  softmax_qr<<<dim3(MP), b256, 0, stream>>>(Sp, QKbf, wkb, mask, Aout, Abf,
                                            Yout);
  // 5. AV = Abf @ Vtb^T -> bf16; Wo transpose rides along (needed next launch)
  gemm_av_wot<<<dim3(1088), b256, 0, stream>>>(Abf, Vtb, AVbf, Wo, WoT);
  // 6. Y: splitK2 atomicAdd into zeroed Yout rows
  gemm_y<<<dim3(16, 4, 2), b256, 0, stream>>>(AVbf, WoT, Yout);
}